// Round 1
// 384.246 us; speedup vs baseline: 1.2114x; 1.2114x over previous
//
#include <hip/hip_runtime.h>
#include <stdint.h>

// C=32 captions, I=32 images, T=40 words, R=36 regions, D=1024.
// R12: algebraic cosine elimination.
//   pn[t]    = sum_d cap[t,d]*wc[t,d] = sum_r P[r,t] * S1raw[r,t]
//              (S1raw = ctx@cap^T == phase-1 raw S of ITER 1; stored to ws)
//   ||wc||^2 = p_t^T G p_t, G = ctx@ctx^T per image (gram_k, bf16 hi+lo split)
// -> phase-2 wc MFMA, ctxT buffer/kernel, capf cosine loads: all deleted.
// Gating MFMA operands swapped (A = cw^T fragment rows=d, B = P cols=t) so
// C-layout yields 4 consecutive d per lane -> packed uint2/float4 pre/capf/
// bias/q2 accesses (~4x fewer VMEM instrs, 512B/store instr vs 128B).
// Softmax by wave 0 only (was 4x redundant); pn/pw/score by wave 1.
// LDS 37888 -> 16896 B.

typedef unsigned short u16;
typedef __attribute__((ext_vector_type(8))) short bf16x8;
typedef __attribute__((ext_vector_type(4))) float f32x4;

#define MFMA_BF16(a, b, c) __builtin_amdgcn_mfma_f32_16x16x32_bf16((a), (b), (c), 0, 0, 0)

__device__ __forceinline__ float bf2f(u16 u) {
  union { unsigned v; float f; } x; x.v = ((unsigned)u) << 16; return x.f;
}
__device__ __forceinline__ u16 f2bf(float f) {  // round-to-nearest-even
  union { float f; unsigned v; } x; x.f = f;
  return (u16)((x.v + 0x7fffu + ((x.v >> 16) & 1u)) >> 16);
}
// async 16B global->LDS (DMA; LDS dest = wave-uniform base + lane*16)
__device__ __forceinline__ void gl2lds16(const u16* g, u16* l) {
  __builtin_amdgcn_global_load_lds((const __attribute__((address_space(1))) void*)g,
                                   (__attribute__((address_space(3))) void*)l, 16, 0, 0);
}

// ---------------------------------------------------------------------------
__global__ void cvt_k(const float* __restrict__ src, u16* __restrict__ dst) {
  const int idx = (blockIdx.x * 256 + threadIdx.x) * 4;
  const float4 v = *(const float4*)(src + idx);
  u16 o[4] = {f2bf(v.x), f2bf(v.y), f2bf(v.z), f2bf(v.w)};
  *(uint2*)(dst + idx) = *(const uint2*)o;
}

// Build cwT[i][d][40] bf16 from cw fp32 [i*36+r][1024]; r pad 36..39 = 0.
__global__ void cwt_k(const float* __restrict__ cw, u16* __restrict__ cwT) {
  const int g = blockIdx.x * 256 + threadIdx.x;  // i*1024+d
  const int i = g >> 10, d = g & 1023;
  u16 row[40];
#pragma unroll
  for (int r = 0; r < 36; ++r) row[r] = f2bf(cw[((size_t)(i * 36 + r) << 10) + d]);
#pragma unroll
  for (int r = 36; r < 40; ++r) row[r] = 0;
  u16* dst = cwT + (size_t)g * 40;
#pragma unroll
  for (int j = 0; j < 5; ++j) *(uint4*)(dst + j * 8) = *(const uint4*)(row + j * 8);
}

// ---------------------------------------------------------------------------
__global__ void capnorm_k(const float* __restrict__ cap, float* __restrict__ cnorm) {
  const int wv = threadIdx.x >> 6, lane = threadIdx.x & 63;
  const int row = blockIdx.x * 4 + wv;  // < 1280
  const float* p = cap + ((size_t)row << 10) + lane * 16;
  float s = 0.f;
#pragma unroll
  for (int e = 0; e < 16; ++e) { float v = p[e]; s += v * v; }
#pragma unroll
  for (int off = 32; off > 0; off >>= 1) s += __shfl_down(s, off, 64);
  if (lane == 0) cnorm[row] = sqrtf(s);
}

// ---------------------------------------------------------------------------
__global__ void transpose_k(const float* __restrict__ Wl, const float* __restrict__ Wg,
                            u16* __restrict__ WTl, u16* __restrict__ WTg) {
  __shared__ u16 tile[32][33];
  const float* src = blockIdx.z ? Wg : Wl;
  u16* dst = blockIdx.z ? WTg : WTl;
  const int k0 = blockIdx.x * 32, n0 = blockIdx.y * 32;
  const int tx = threadIdx.x, ty = threadIdx.y;
#pragma unroll
  for (int j = 0; j < 4; ++j)
    tile[ty + 8 * j][tx] = f2bf(src[(size_t)(k0 + ty + 8 * j) * 1024 + n0 + tx]);
  __syncthreads();
#pragma unroll
  for (int j = 0; j < 4; ++j)
    dst[(size_t)(n0 + ty + 8 * j) * 2048 + k0 + tx] = tile[tx][ty + 8 * j];
}

// ---------------------------------------------------------------------------
// Dual-B GEMM: out{L,G}[m,n] = sum_k A[m,k]*W{l,g}[kofs+k][n], K=1024.
template <int IMGW>
__global__ __launch_bounds__(256, 2) void gemm_w(
    const u16* __restrict__ A, const u16* __restrict__ WTl, const u16* __restrict__ WTg,
    void* __restrict__ outL_, void* __restrict__ outG_) {
  __shared__ __align__(16) u16 lsA[128 * 32];
  __shared__ __align__(16) u16 lsBl[128 * 32];
  __shared__ __align__(16) u16 lsBg[128 * 32];
  const int tid = threadIdx.x;
  const int bm = blockIdx.x >> 3, bn = blockIdx.x & 7;
  const int wv = tid >> 6, lane = tid & 63;
  const int quad = lane >> 4, l15 = lane & 15;
  const int wm = (wv & 1) << 6, wn = (wv >> 1) << 6;
  const int kofs = IMGW ? 1024 : 0;

  f32x4 accL[4][4], accG[4][4];
#pragma unroll
  for (int a = 0; a < 4; ++a)
#pragma unroll
    for (int b = 0; b < 4; ++b) {
      accL[a][b] = (f32x4){0.f, 0.f, 0.f, 0.f};
      accG[a][b] = (f32x4){0.f, 0.f, 0.f, 0.f};
    }

  const size_t arow0 = (size_t)bm * 128 * 1024;
  for (int kt = 0; kt < 32; ++kt) {
    if (kt) __syncthreads();
#pragma unroll
    for (int s = 0; s < 2; ++s) {
      const int idx = s * 256 + tid;
      const int row = idx >> 2, c8 = idx & 3;
      gl2lds16(A + arow0 + (size_t)row * 1024 + kt * 32 + c8 * 8,
               lsA + (size_t)(s * 256 + wv * 64) * 8);
      const size_t bro = (size_t)(bn * 128 + row) * 2048 + kofs + kt * 32 + c8 * 8;
      gl2lds16(WTl + bro, lsBl + (size_t)(s * 256 + wv * 64) * 8);
      gl2lds16(WTg + bro, lsBg + (size_t)(s * 256 + wv * 64) * 8);
    }
    __syncthreads();
    bf16x8 af[4], bl8[4], bg8[4];
#pragma unroll
    for (int mt = 0; mt < 4; ++mt)
      af[mt] = *(const bf16x8*)(lsA + (wm + mt * 16 + l15) * 32 + quad * 8);
#pragma unroll
    for (int nt = 0; nt < 4; ++nt) {
      bl8[nt] = *(const bf16x8*)(lsBl + (wn + nt * 16 + l15) * 32 + quad * 8);
      bg8[nt] = *(const bf16x8*)(lsBg + (wn + nt * 16 + l15) * 32 + quad * 8);
    }
#pragma unroll
    for (int mt = 0; mt < 4; ++mt)
#pragma unroll
      for (int nt = 0; nt < 4; ++nt) {
        accL[mt][nt] = MFMA_BF16(af[mt], bl8[nt], accL[mt][nt]);
        accG[mt][nt] = MFMA_BF16(af[mt], bg8[nt], accG[mt][nt]);
      }
  }
#pragma unroll
  for (int mt = 0; mt < 4; ++mt)
#pragma unroll
    for (int nt = 0; nt < 4; ++nt)
#pragma unroll
      for (int r = 0; r < 4; ++r) {
        const int m = bm * 128 + wm + mt * 16 + quad * 4 + r;
        const int n = bn * 128 + wn + nt * 16 + l15;
        if (IMGW) {
          ((float*)outL_)[(size_t)m * 1024 + n] = accL[mt][nt][r];
          ((float*)outG_)[(size_t)m * 1024 + n] = accG[mt][nt][r];
        } else {
          ((u16*)outL_)[(size_t)m * 1024 + n] = f2bf(accL[mt][nt][r]);
          ((u16*)outG_)[(size_t)m * 1024 + n] = f2bf(accG[mt][nt][r]);
        }
      }
}

// ---------------------------------------------------------------------------
// Per-image Gram: G[i] = ctx_i @ ctx_i^T [36x36], stored [48 rows][64 cols]
// bf16 as hi+lo split (fp32-class). Row/col >= 36 zero; cols 48..63 zero.
// Stored transposed via symmetry so the f32x4 readback packs.
__global__ __launch_bounds__(256, 2) void gram_k(const u16* __restrict__ imgb,
                                                 u16* __restrict__ Ghi,
                                                 u16* __restrict__ Glo) {
  __shared__ float lsS[48 * 52];
  const int tid = threadIdx.x;
  const int i = blockIdx.x;
  const int wv = tid >> 6, lane = tid & 63;
  const int quad = lane >> 4, l15 = lane & 15;
  for (int k = tid; k < 48 * 52; k += 256) lsS[k] = 0.f;

  const u16* arow[3]; bool avalid[3];
#pragma unroll
  for (int mt = 0; mt < 3; ++mt) {
    const int r = mt * 16 + l15;
    avalid[mt] = r < 36;
    arow[mt] = imgb + ((size_t)(i * 36 + (r < 36 ? r : 35)) << 10);
  }
  const bf16x8 zero8 = {0, 0, 0, 0, 0, 0, 0, 0};
  f32x4 acc[3][3];
#pragma unroll
  for (int a = 0; a < 3; ++a)
#pragma unroll
    for (int b = 0; b < 3; ++b) acc[a][b] = (f32x4){0.f, 0.f, 0.f, 0.f};

  for (int kk = wv * 8; kk < wv * 8 + 8; ++kk) {
    const int ko = kk * 32 + quad * 8;
    bf16x8 af[3];
#pragma unroll
    for (int mt = 0; mt < 3; ++mt)
      af[mt] = avalid[mt] ? *(const bf16x8*)(arow[mt] + ko) : zero8;
#pragma unroll
    for (int mt = 0; mt < 3; ++mt)
#pragma unroll
      for (int nt = 0; nt < 3; ++nt)
        acc[mt][nt] = MFMA_BF16(af[mt], af[nt], acc[mt][nt]);
  }
  __syncthreads();
#pragma unroll
  for (int mt = 0; mt < 3; ++mt)
#pragma unroll
    for (int nt = 0; nt < 3; ++nt)
#pragma unroll
      for (int rg = 0; rg < 4; ++rg)
        atomicAdd(&lsS[(nt * 16 + l15) * 52 + mt * 16 + quad * 4 + rg],
                  acc[mt][nt][rg]);
  __syncthreads();
  if (wv == 0) {
#pragma unroll
    for (int nt = 0; nt < 3; ++nt) {
      const int rp = nt * 16 + l15;  // stored row (G symmetric)
#pragma unroll
      for (int mt = 0; mt < 3; ++mt) {
        const f32x4 g = *(const f32x4*)&lsS[rp * 52 + mt * 16 + quad * 4];
        u16 hv[4], lv[4];
#pragma unroll
        for (int rg = 0; rg < 4; ++rg) {
          hv[rg] = f2bf(g[rg]);
          lv[rg] = f2bf(g[rg] - bf2f(hv[rg]));
        }
        const size_t gb = ((size_t)i * 48 + rp) * 64 + mt * 16 + quad * 4;
        *(uint2*)(Ghi + gb) = *(const uint2*)hv;
        *(uint2*)(Glo + gb) = *(const uint2*)lv;
      }
    }
  }
  for (int k = tid; k < 48 * 16; k += 256) {  // zero cols 48..63
    const size_t gb = ((size_t)i * 48 + (k >> 4)) * 64 + 48 + (k & 15);
    Ghi[gb] = 0; Glo[gb] = 0;
  }
}

// ---------------------------------------------------------------------------
// Fused attention. ITER 1: query=cap; sim1; q2 = gate(P.cwT + pre + b);
// stores S1raw. ITER 2: query=q2; score = sim1 + sim2 via S1raw + Gram.
template <int ITER>
__global__ __launch_bounds__(256, 2) void attn_k(
    const u16* __restrict__ imgb, const u16* __restrict__ capb,
    const u16* __restrict__ q2v, const u16* __restrict__ cwTL,
    const u16* __restrict__ cwTG, const u16* __restrict__ preL,
    const u16* __restrict__ preG, const float* __restrict__ capf,
    const float* __restrict__ bL, const float* __restrict__ bG,
    u16* __restrict__ q2o, const float* __restrict__ cnorm,
    const u16* __restrict__ Ghi, const u16* __restrict__ Glo,
    float* __restrict__ s1raw, float* __restrict__ sim1,
    float* __restrict__ score) {
  __shared__ __align__(16) u16 lsAT[48 * 72];   // P [t][r] bf16 (single copy)
  __shared__ __align__(16) float lsS[48 * 52];  // S [t][r] f32, stride 52 (16B rows)

  const int tid = threadIdx.x;
  const int c = blockIdx.x >> 5, i = blockIdx.x & 31;
  const int pair = c * 32 + i;
  const int wv = tid >> 6, lane = tid & 63;
  const int quad = lane >> 4, l15 = lane & 15;

  for (int k = tid; k < 48 * 72 / 2; k += 256) ((unsigned*)lsAT)[k] = 0u;
  for (int k = tid; k < 48 * 52; k += 256) lsS[k] = 0.f;

  const u16* arow[3]; bool avalid[3];
  const u16* brow[3]; bool bvalid[3];
#pragma unroll
  for (int mt = 0; mt < 3; ++mt) {
    const int r = mt * 16 + l15;
    avalid[mt] = r < 36;
    arow[mt] = imgb + ((size_t)(i * 36 + (r < 36 ? r : 35)) << 10);
  }
#pragma unroll
  for (int nt = 0; nt < 3; ++nt) {
    const int t = nt * 16 + l15;
    bvalid[nt] = t < 40;
    const int tc = t < 40 ? t : 39;
    brow[nt] = (ITER == 1) ? (capb + ((size_t)(c * 40 + tc) << 10))
                           : (q2v + ((size_t)(pair * 40 + tc) << 10));
  }
  const bf16x8 zero8 = {0, 0, 0, 0, 0, 0, 0, 0};

  // ---- phase 1: partial S over this wave's K-range
  f32x4 accS[3][3];
#pragma unroll
  for (int a = 0; a < 3; ++a)
#pragma unroll
    for (int b = 0; b < 3; ++b) accS[a][b] = (f32x4){0.f, 0.f, 0.f, 0.f};

  for (int kk = wv * 8; kk < wv * 8 + 8; ++kk) {
    const int ko = kk * 32 + quad * 8;
    bf16x8 af[3], bq[3];
#pragma unroll
    for (int mt = 0; mt < 3; ++mt)
      af[mt] = avalid[mt] ? *(const bf16x8*)(arow[mt] + ko) : zero8;
#pragma unroll
    for (int nt = 0; nt < 3; ++nt)
      bq[nt] = bvalid[nt] ? *(const bf16x8*)(brow[nt] + ko) : zero8;
#pragma unroll
    for (int mt = 0; mt < 3; ++mt)
#pragma unroll
      for (int nt = 0; nt < 3; ++nt)
        accS[mt][nt] = MFMA_BF16(af[mt], bq[nt], accS[mt][nt]);
  }
  __syncthreads();  // zeros visible
#pragma unroll
  for (int mt = 0; mt < 3; ++mt)
#pragma unroll
    for (int nt = 0; nt < 3; ++nt)
#pragma unroll
      for (int rg = 0; rg < 4; ++rg)
        atomicAdd(&lsS[(nt * 16 + l15) * 52 + mt * 16 + quad * 4 + rg],
                  accS[mt][nt][rg]);
  __syncthreads();

  // ---- softmax: wave 0 only (all waves were computing identical results)
  if (wv == 0) {
    float sS[3][3][4];
#pragma unroll
    for (int mt = 0; mt < 3; ++mt)
#pragma unroll
      for (int nt = 0; nt < 3; ++nt) {
        const f32x4 v = *(const f32x4*)&lsS[(nt * 16 + l15) * 52 + mt * 16 + quad * 4];
#pragma unroll
        for (int rg = 0; rg < 4; ++rg) sS[mt][nt][rg] = v[rg];
      }
    float rn[3][4];
#pragma unroll
    for (int mt = 0; mt < 3; ++mt)
#pragma unroll
      for (int rg = 0; rg < 4; ++rg) {
        float s2 = 0.f;
#pragma unroll
        for (int nt = 0; nt < 3; ++nt) {
          float v = sS[mt][nt][rg]; v = v > 0.f ? v : 0.1f * v; s2 += v * v;
        }
        s2 += __shfl_xor(s2, 1, 64); s2 += __shfl_xor(s2, 2, 64);
        s2 += __shfl_xor(s2, 4, 64); s2 += __shfl_xor(s2, 8, 64);
        rn[mt][rg] = sqrtf(s2) + 1e-8f;
      }
    float mx[3] = {-3.0e38f, -3.0e38f, -3.0e38f};
#pragma unroll
    for (int mt = 0; mt < 3; ++mt)
#pragma unroll
      for (int nt = 0; nt < 3; ++nt)
#pragma unroll
        for (int rg = 0; rg < 4; ++rg) {
          const int r = mt * 16 + quad * 4 + rg;
          float v = sS[mt][nt][rg]; v = v > 0.f ? v : 0.1f * v;
          float zz = 9.f * v / rn[mt][rg];
          zz = (r < 36) ? zz : -3.0e38f;
          sS[mt][nt][rg] = zz;
          mx[nt] = fmaxf(mx[nt], zz);
        }
#pragma unroll
    for (int nt = 0; nt < 3; ++nt) {
      mx[nt] = fmaxf(mx[nt], __shfl_xor(mx[nt], 16, 64));
      mx[nt] = fmaxf(mx[nt], __shfl_xor(mx[nt], 32, 64));
    }
    float ss[3] = {0.f, 0.f, 0.f};
#pragma unroll
    for (int mt = 0; mt < 3; ++mt)
#pragma unroll
      for (int nt = 0; nt < 3; ++nt)
#pragma unroll
        for (int rg = 0; rg < 4; ++rg) {
          const float e = __expf(sS[mt][nt][rg] - mx[nt]);
          sS[mt][nt][rg] = e; ss[nt] += e;
        }
#pragma unroll
    for (int nt = 0; nt < 3; ++nt) {
      ss[nt] += __shfl_xor(ss[nt], 16, 64);
      ss[nt] += __shfl_xor(ss[nt], 32, 64);
      ss[nt] = 1.f / ss[nt];
    }
#pragma unroll
    for (int nt = 0; nt < 3; ++nt) {
      const int t = nt * 16 + l15;
      if (t < 40) {
#pragma unroll
        for (int mt = 0; mt < 3; ++mt) {
          u16 pv[4];
#pragma unroll
          for (int rg = 0; rg < 4; ++rg) pv[rg] = f2bf(sS[mt][nt][rg] * ss[nt]);
          *(uint2*)(lsAT + t * 72 + mt * 16 + quad * 4) = *(const uint2*)pv;
        }
      }
    }
  }
  __syncthreads();

  // P fragments (B-operand: col=t=l15, k=r). Needed by gating (ITER1, all
  // waves) and by the Gram path (wave 1).
  bf16x8 afA[3][2];
  if (ITER == 1 || wv == 1) {
#pragma unroll
    for (int mtT = 0; mtT < 3; ++mtT)
#pragma unroll
      for (int ks = 0; ks < 2; ++ks)
        afA[mtT][ks] =
            *(const bf16x8*)(lsAT + (mtT * 16 + l15) * 72 + ks * 32 + quad * 8);
  }

  // ---- wave 1: pn via S1raw, pw via Gram, score write
  if (wv == 1) {
    float pf[3][3][4];
    float pnv[3] = {0.f, 0.f, 0.f}, pwv[3] = {0.f, 0.f, 0.f};
#pragma unroll
    for (int nt = 0; nt < 3; ++nt) {
      const int t = nt * 16 + l15;
#pragma unroll
      for (int mt = 0; mt < 3; ++mt) {
        const uint2 p2 = *(const uint2*)(lsAT + t * 72 + mt * 16 + quad * 4);
        pf[mt][nt][0] = bf2f((u16)(p2.x & 0xffffu));
        pf[mt][nt][1] = bf2f((u16)(p2.x >> 16));
        pf[mt][nt][2] = bf2f((u16)(p2.y & 0xffffu));
        pf[mt][nt][3] = bf2f((u16)(p2.y >> 16));
        f32x4 s1;
        if (ITER == 1) {
          s1 = *(const f32x4*)&lsS[t * 52 + mt * 16 + quad * 4];
          *(f32x4*)(s1raw + ((size_t)pair * 48 + t) * 48 + mt * 16 + quad * 4) = s1;
        } else {
          s1 = *(const f32x4*)(s1raw + ((size_t)pair * 48 + t) * 48 + mt * 16 + quad * 4);
        }
#pragma unroll
        for (int rg = 0; rg < 4; ++rg) pnv[nt] += pf[mt][nt][rg] * s1[rg];
      }
    }
    f32x4 gp[3][3];
#pragma unroll
    for (int a = 0; a < 3; ++a)
#pragma unroll
      for (int b = 0; b < 3; ++b) gp[a][b] = (f32x4){0.f, 0.f, 0.f, 0.f};
#pragma unroll
    for (int ks = 0; ks < 2; ++ks)
#pragma unroll
      for (int mtG = 0; mtG < 3; ++mtG) {
        const size_t gb = ((size_t)i * 48 + mtG * 16 + l15) * 64 + ks * 32 + quad * 8;
        const bf16x8 gh = *(const bf16x8*)(Ghi + gb);
        const bf16x8 gl = *(const bf16x8*)(Glo + gb);
#pragma unroll
        for (int mtT = 0; mtT < 3; ++mtT) {
          gp[mtG][mtT] = MFMA_BF16(gh, afA[mtT][ks], gp[mtG][mtT]);
          gp[mtG][mtT] = MFMA_BF16(gl, afA[mtT][ks], gp[mtG][mtT]);
        }
      }
#pragma unroll
    for (int nt = 0; nt < 3; ++nt)
#pragma unroll
      for (int mt = 0; mt < 3; ++mt)
#pragma unroll
        for (int rg = 0; rg < 4; ++rg)
          pwv[nt] += pf[mt][nt][rg] * gp[mt][nt][rg];
#pragma unroll
    for (int nt = 0; nt < 3; ++nt) {
      pnv[nt] += __shfl_xor(pnv[nt], 16, 64); pnv[nt] += __shfl_xor(pnv[nt], 32, 64);
      pwv[nt] += __shfl_xor(pwv[nt], 16, 64); pwv[nt] += __shfl_xor(pwv[nt], 32, 64);
    }
    float tot = 0.f;
#pragma unroll
    for (int nt = 0; nt < 3; ++nt) {
      const int t = nt * 16 + l15;
      if (t < 40) {
        const float w2 = sqrtf(fmaxf(pwv[nt], 0.f));
        tot += pnv[nt] / fmaxf(cnorm[c * 40 + t] * w2, 1e-8f);
      }
    }
    tot += __shfl_xor(tot, 1, 64); tot += __shfl_xor(tot, 2, 64);
    tot += __shfl_xor(tot, 4, 64); tot += __shfl_xor(tot, 8, 64);
    if (lane == 0) {
      const float s = tot * (1.f / 40.f);
      if (ITER == 1) sim1[pair] = s;
      else score[i * 32 + c] = s + sim1[pair];
    }
  }

  // ---- gating (ITER 1 only, all waves): swapped operands -> lane holds
  // 4 consecutive d (row=quad*4+rg) for one t (col=l15).
  if (ITER == 1) {
    const int dbase = wv * 256;
    const u16* pLp[3]; const u16* pGp[3]; const float* cfp[3]; u16* qop[3];
    bool tval[3];
#pragma unroll
    for (int mtT = 0; mtT < 3; ++mtT) {
      const int t = mtT * 16 + l15;
      tval[mtT] = t < 40;
      const int tc = t < 40 ? t : 39;
      const size_t ctd = ((size_t)(c * 40 + tc) << 10) + dbase + quad * 4;
      pLp[mtT] = preL + ctd; pGp[mtT] = preG + ctd; cfp[mtT] = capf + ctd;
      qop[mtT] = q2o + (((size_t)(pair * 40 + tc)) << 10) + dbase + quad * 4;
    }
    const u16* cwl = cwTL + ((size_t)(i << 10) + dbase + l15) * 40;
    const u16* cwg = cwTG + ((size_t)(i << 10) + dbase + l15) * 40;
    const float* bLp = bL + dbase + quad * 4;
    const float* bGp = bG + dbase + quad * 4;
    for (int nt2 = 0; nt2 < 16; ++nt2) {
      const bf16x8 cl0 = *(const bf16x8*)(cwl + quad * 8);
      const bf16x8 cl1 = *(const bf16x8*)(cwl + 32 + quad * 8);  // overrun: P=0 there
      const bf16x8 cg0 = *(const bf16x8*)(cwg + quad * 8);
      const bf16x8 cg1 = *(const bf16x8*)(cwg + 32 + quad * 8);
      cwl += 16 * 40; cwg += 16 * 40;
      const f32x4 bl4 = *(const f32x4*)bLp;  bLp += 16;
      const f32x4 bg4 = *(const f32x4*)bGp;  bGp += 16;
      f32x4 aqL[3], aqG[3];
#pragma unroll
      for (int mtT = 0; mtT < 3; ++mtT) {
        f32x4 z = (f32x4){0.f, 0.f, 0.f, 0.f};
        z = MFMA_BF16(cl0, afA[mtT][0], z);
        aqL[mtT] = MFMA_BF16(cl1, afA[mtT][1], z);
        f32x4 z2 = (f32x4){0.f, 0.f, 0.f, 0.f};
        z2 = MFMA_BF16(cg0, afA[mtT][0], z2);
        aqG[mtT] = MFMA_BF16(cg1, afA[mtT][1], z2);
      }
#pragma unroll
      for (int mtT = 0; mtT < 3; ++mtT) {
        if (tval[mtT]) {
          const uint2 plv = *(const uint2*)pLp[mtT];
          const uint2 pgv = *(const uint2*)pGp[mtT];
          const f32x4 cf = *(const f32x4*)cfp[mtT];
          const float pl4[4] = {bf2f((u16)(plv.x & 0xffffu)), bf2f((u16)(plv.x >> 16)),
                                bf2f((u16)(plv.y & 0xffffu)), bf2f((u16)(plv.y >> 16))};
          const float pg4[4] = {bf2f((u16)(pgv.x & 0xffffu)), bf2f((u16)(pgv.x >> 16)),
                                bf2f((u16)(pgv.y & 0xffffu)), bf2f((u16)(pgv.y >> 16))};
          u16 ov[4];
#pragma unroll
          for (int rg = 0; rg < 4; ++rg) {
            const float aL = aqL[mtT][rg] + pl4[rg] + bl4[rg];
            const float aG = aqG[mtT][rg] + pg4[rg] + bg4[rg];
            const float g = 1.f / (1.f + __expf(-aG));
            const float u = 2.f / (1.f + __expf(-2.f * aL)) - 1.f;  // tanh
            ov[rg] = f2bf(cf[rg] * g + u * (1.f - g));
          }
          *(uint2*)qop[mtT] = *(const uint2*)ov;
        }
        pLp[mtT] += 16; pGp[mtT] += 16; cfp[mtT] += 16; qop[mtT] += 16;
      }
    }
  }
}

// ---------------------------------------------------------------------------
extern "C" void kernel_launch(void* const* d_in, const int* in_sizes, int n_in,
                              void* d_out, int out_size, void* d_ws, size_t ws_size,
                              hipStream_t stream) {
  const float* img = (const float*)d_in[0];   // [32][36][1024] fp32
  const float* cap = (const float*)d_in[1];   // [32][40][1024] fp32
  const float* Wl  = (const float*)d_in[2];   // [2048][1024] fp32
  const float* bl  = (const float*)d_in[3];   // [1024] fp32
  const float* Wg  = (const float*)d_in[4];
  const float* bg  = (const float*)d_in[5];
  float* out = (float*)d_out;                 // [32][32] fp32

  char* ws = (char*)d_ws;
  float* cnrm = (float*)ws;               ws += 5120;
  float* sim1 = (float*)ws;               ws += 4096;
  u16*   WTl  = (u16*)ws;                 ws += (size_t)1024 * 2048 * 2;   // 4.2 MB
  u16*   WTg  = (u16*)ws;                 ws += (size_t)1024 * 2048 * 2;   // 4.2 MB
  u16*   preL = (u16*)ws;                 ws += (size_t)1280 * 1024 * 2;   // 2.6 MB
  u16*   preG = (u16*)ws;                 ws += (size_t)1280 * 1024 * 2;   // 2.6 MB
  u16*   imgb = (u16*)ws;                 ws += (size_t)1152 * 1024 * 2;   // 2.4 MB
  u16*   capb = (u16*)ws;                 ws += (size_t)1280 * 1024 * 2;   // 2.6 MB
  u16*   Ghi  = (u16*)ws;                 ws += (size_t)32 * 48 * 64 * 2;  // 196 KB
  u16*   Glo  = (u16*)ws;                 ws += (size_t)32 * 48 * 64 * 2;  // 196 KB
  u16*   cwTL = (u16*)ws;                 ws += (size_t)32 * 1024 * 40 * 2 + 256;
  u16*   cwTG = (u16*)ws;                 ws += (size_t)32 * 1024 * 40 * 2 + 256;
  float* cwL  = (float*)ws;               ws += (size_t)1152 * 1024 * 4;   // 4.7 MB
  float* cwG  = (float*)ws;               ws += (size_t)1152 * 1024 * 4;   // 4.7 MB
  u16*   q2   = (u16*)ws;                 ws += (size_t)40960 * 1024 * 2;  // 83.9 MB
  // S1raw [1024 pairs][48 t][48 r] fp32 = 9.44 MB, exactly cwL+cwG (dead
  // after cwt_k, which runs before attn_k<1>).
  float* s1raw = cwL;

  cvt_k<<<1152, 256, 0, stream>>>(img, imgb);
  cvt_k<<<1280, 256, 0, stream>>>(cap, capb);
  transpose_k<<<dim3(64, 32, 2), dim3(32, 8), 0, stream>>>(Wl, Wg, WTl, WTg);
  capnorm_k<<<320, 256, 0, stream>>>(cap, cnrm);
  gram_k<<<32, 256, 0, stream>>>(imgb, Ghi, Glo);
  gemm_w<0><<<80, 256, 0, stream>>>(capb, WTl, WTg, preL, preG);   // cap@W_top
  gemm_w<1><<<72, 256, 0, stream>>>(imgb, WTl, WTg, cwL, cwG);     // img@W_bot
  cwt_k<<<128, 256, 0, stream>>>(cwL, cwTL);
  cwt_k<<<128, 256, 0, stream>>>(cwG, cwTG);
  attn_k<1><<<1024, 256, 0, stream>>>(imgb, capb, q2, cwTL, cwTG, preL, preG,
                                      cap, bl, bg, q2, cnrm, Ghi, Glo, s1raw,
                                      sim1, out);
  attn_k<2><<<1024, 256, 0, stream>>>(imgb, capb, q2, cwTL, cwTG, preL, preG,
                                      cap, bl, bg, q2, cnrm, Ghi, Glo, s1raw,
                                      sim1, out);
}